// Round 4
// baseline (219.030 us; speedup 1.0000x reference)
//
#include <hip/hip_runtime.h>
#include <hip/hip_bf16.h>

#define N_ROWS 16384
#define D_COLS 2048
#define NUM_LABELS 1024
#define NUM_CAMS 8
#define NUM_SEG (NUM_LABELS * NUM_CAMS)   // 8192
#define MAXPER 64                          // list capacity per segment (true max ~12 here)
#define F4_PER_ROW (D_COLS / 4)            // 512 float4 per row
#define NUM_WAVES (NUM_SEG * 2)            // one wave per (segment, column-half)

// ---------------- kernel 1: build per-segment row lists ----------------
__global__ void build_lists_kernel(const int* __restrict__ labels,
                                   const int* __restrict__ cams,
                                   int* __restrict__ counts,
                                   int* __restrict__ lists) {
    int i = blockIdx.x * blockDim.x + threadIdx.x;
    if (i < N_ROWS) {
        int seg = labels[i] * NUM_CAMS + cams[i];
        int pos = atomicAdd(&counts[seg], 1);
        if (pos < MAXPER) lists[seg * MAXPER + pos] = i;
    }
}

__device__ __forceinline__ float smooth_l1(float d) {
    float ad = fabsf(d);
    return ad < 1.0f ? 0.5f * d * d : ad - 0.5f;
}

// ---------------- kernel 2: one WAVE per (segment, column-half) ----------------
// Lane owns 4 float4 chunks: col float4 index = half*256 + k*64 + lane, k=0..3.
// No LDS, no __syncthreads, no atomics. Row indices preloaded one-per-lane and
// broadcast with __shfl. Mean is per-lane (no reduction). Loss wave-reduced.
__global__ __launch_bounds__(256) void seg_loss_kernel(const float* __restrict__ feats,
                                                       const int* __restrict__ counts,
                                                       const int* __restrict__ lists,
                                                       float* __restrict__ partials) {
    int wave = (blockIdx.x * 256 + threadIdx.x) >> 6;   // 0..NUM_WAVES-1
    int lane = threadIdx.x & 63;
    int seg  = wave >> 1;
    int half = wave & 1;
    int cnt  = counts[seg];
    float loss = 0.0f;

    if (cnt > 0) {
        int rows = cnt < MAXPER ? cnt : MAXPER;

        // each lane preloads one row index; broadcast later via shuffle
        int myidx = (lane < rows) ? lists[seg * MAXPER + lane] : 0;

        const float4* base = (const float4*)feats;
        int coff = half * 256 + lane;   // this lane's first float4 column index

        float s0x=0.f,s0y=0.f,s0z=0.f,s0w=0.f;
        float s1x=0.f,s1y=0.f,s1z=0.f,s1w=0.f;
        float s2x=0.f,s2y=0.f,s2z=0.f,s2w=0.f;
        float s3x=0.f,s3y=0.f,s3z=0.f,s3w=0.f;

        // pass 1: sum over rows — 4 independent loads in flight per row
        for (int r = 0; r < rows; ++r) {
            int row = __shfl(myidx, r, 64);
            const float4* rp = base + (size_t)row * F4_PER_ROW + coff;
            float4 t0 = rp[0];
            float4 t1 = rp[64];
            float4 t2 = rp[128];
            float4 t3 = rp[192];
            s0x += t0.x; s0y += t0.y; s0z += t0.z; s0w += t0.w;
            s1x += t1.x; s1y += t1.y; s1z += t1.z; s1w += t1.w;
            s2x += t2.x; s2y += t2.y; s2z += t2.z; s2w += t2.w;
            s3x += t3.x; s3y += t3.y; s3z += t3.z; s3w += t3.w;
        }
        float inv = 1.0f / (float)cnt;
        s0x*=inv; s0y*=inv; s0z*=inv; s0w*=inv;
        s1x*=inv; s1y*=inv; s1z*=inv; s1w*=inv;
        s2x*=inv; s2y*=inv; s2z*=inv; s2w*=inv;
        s3x*=inv; s3y*=inv; s3z*=inv; s3w*=inv;

        // pass 2: SmoothL1 vs mean (same addresses — L1/L2 hot)
        for (int r = 0; r < rows; ++r) {
            int row = __shfl(myidx, r, 64);
            const float4* rp = base + (size_t)row * F4_PER_ROW + coff;
            float4 t0 = rp[0];
            float4 t1 = rp[64];
            float4 t2 = rp[128];
            float4 t3 = rp[192];
            loss += smooth_l1(t0.x - s0x) + smooth_l1(t0.y - s0y)
                  + smooth_l1(t0.z - s0z) + smooth_l1(t0.w - s0w);
            loss += smooth_l1(t1.x - s1x) + smooth_l1(t1.y - s1y)
                  + smooth_l1(t1.z - s1z) + smooth_l1(t1.w - s1w);
            loss += smooth_l1(t2.x - s2x) + smooth_l1(t2.y - s2y)
                  + smooth_l1(t2.z - s2z) + smooth_l1(t2.w - s2w);
            loss += smooth_l1(t3.x - s3x) + smooth_l1(t3.y - s3y)
                  + smooth_l1(t3.z - s3z) + smooth_l1(t3.w - s3w);
        }
    }

    // wave-level reduction only (no LDS, no barrier)
    for (int o = 32; o > 0; o >>= 1)
        loss += __shfl_down(loss, o, 64);
    if (lane == 0)
        partials[wave] = loss;   // plain store; every wave writes (0 if empty)
}

// ---------------- kernel 3: reduce partials -> scalar loss ----------------
__global__ __launch_bounds__(256) void reduce_kernel(const float* __restrict__ partials,
                                                     float* __restrict__ out) {
    int tid = threadIdx.x;
    float s = 0.0f;
    for (int i = tid; i < NUM_WAVES; i += 256)
        s += partials[i];

    for (int o = 32; o > 0; o >>= 1)
        s += __shfl_down(s, o, 64);

    __shared__ float wsum[4];
    int lane = tid & 63;
    int wid  = tid >> 6;
    if (lane == 0) wsum[wid] = s;
    __syncthreads();
    if (tid == 0)
        out[0] = (wsum[0] + wsum[1] + wsum[2] + wsum[3])
               * (1.0f / ((float)N_ROWS * (float)D_COLS));
}

extern "C" void kernel_launch(void* const* d_in, const int* in_sizes, int n_in,
                              void* d_out, int out_size, void* d_ws, size_t ws_size,
                              hipStream_t stream) {
    const float* feats = (const float*)d_in[0];
    const int* labels  = (const int*)d_in[1];
    const int* cams    = (const int*)d_in[2];
    float* out = (float*)d_out;

    // workspace layout: counts[NUM_SEG] | lists[NUM_SEG*MAXPER] | partials[NUM_WAVES]
    int* counts     = (int*)d_ws;
    int* lists      = counts + NUM_SEG;
    float* partials = (float*)(lists + NUM_SEG * MAXPER);

    hipMemsetAsync(counts, 0, NUM_SEG * sizeof(int), stream);   // only counts need zeroing

    build_lists_kernel<<<(N_ROWS + 255) / 256, 256, 0, stream>>>(labels, cams, counts, lists);
    seg_loss_kernel<<<NUM_WAVES * 64 / 256, 256, 0, stream>>>(feats, counts, lists, partials);
    reduce_kernel<<<1, 256, 0, stream>>>(partials, out);
}